// Round 3
// baseline (1534.724 us; speedup 1.0000x reference)
//
#include <hip/hip_runtime.h>

#define DIM 128

// ---------------- degree ----------------
__global__ __launch_bounds__(256) void deg_kernel(const int* __restrict__ dst,
                                                  int E, int n, float* __restrict__ deg) {
    int e = blockIdx.x * 256 + threadIdx.x;
    if (e < E) {
        int d = min(max(dst[e], 0), n - 1);
        atomicAdd(&deg[d], 1.0f);
    }
}

__global__ __launch_bounds__(256) void dinv_kernel(float* __restrict__ deg, int n) {
    int i = blockIdx.x * 256 + threadIdx.x;
    if (i < n) deg[i] = rsqrtf(deg[i] + 1.0f);   // deg includes +1 self-loop
}

// ---------------- GEMM1: hs[r][c] = dinv[r] * sum_k x[r][k]*W[k][c] ----------------
// block = 256 threads, 64 rows/block. W1 (64KB) + x-tile (32KB) staged in LDS.
// Each thread computes 8 rows x 4 cols.
__global__ __launch_bounds__(256) void gemm1_kernel(const float* __restrict__ x,
                                                    const float* __restrict__ W,
                                                    const float* __restrict__ dinv,
                                                    float* __restrict__ hs, int n) {
    __shared__ float Ws[DIM][DIM];   // 64 KB
    __shared__ float xs[64][DIM];    // 32 KB
    const int tid = threadIdx.x;

    for (int i = tid; i < DIM * DIM / 4; i += 256)
        ((float4*)Ws)[i] = ((const float4*)W)[i];

    const int row0 = blockIdx.x * 64;
    for (int i = tid; i < 64 * DIM / 4; i += 256) {
        int r = i >> 5, c = i & 31;
        int gr = row0 + r;
        float4 v = make_float4(0.f, 0.f, 0.f, 0.f);
        if (gr < n) v = ((const float4*)(x + (size_t)gr * DIM))[c];
        ((float4*)(&xs[r][0]))[c] = v;
    }
    __syncthreads();

    const int tx = tid & 31;   // cols 4*tx .. 4*tx+3
    const int ty = tid >> 5;   // rows 8*ty .. 8*ty+7
    float acc[8][4];
#pragma unroll
    for (int r = 0; r < 8; ++r)
#pragma unroll
        for (int c = 0; c < 4; ++c) acc[r][c] = 0.f;

#pragma unroll 4
    for (int k = 0; k < DIM; ++k) {
        float4 wv = ((float4*)(&Ws[k][0]))[tx];
#pragma unroll
        for (int r = 0; r < 8; ++r) {
            float xv = xs[ty * 8 + r][k];
            acc[r][0] = fmaf(xv, wv.x, acc[r][0]);
            acc[r][1] = fmaf(xv, wv.y, acc[r][1]);
            acc[r][2] = fmaf(xv, wv.z, acc[r][2]);
            acc[r][3] = fmaf(xv, wv.w, acc[r][3]);
        }
    }

#pragma unroll
    for (int r = 0; r < 8; ++r) {
        int gr = row0 + ty * 8 + r;
        if (gr < n) {
            float dv = dinv[gr];
            float4 v = make_float4(acc[r][0] * dv, acc[r][1] * dv,
                                   acc[r][2] * dv, acc[r][3] * dv);
            ((float4*)(hs + (size_t)gr * DIM))[tx] = v;
        }
    }
}

// ---------------- scatter layer 1: agg[dst] += hs[src], 32 threads/edge ----------------
__global__ __launch_bounds__(256) void scatter1_kernel(const int* __restrict__ src,
                                                       const int* __restrict__ dst,
                                                       int E, int n,
                                                       const float* __restrict__ hs,
                                                       float* __restrict__ agg) {
    long long g = (long long)blockIdx.x * 256 + threadIdx.x;
    int e = (int)(g >> 5);
    if (e >= E) return;
    int t = (int)(g & 31);           // handles dims 4t..4t+3
    int s = min(max(src[e], 0), n - 1);
    int d = min(max(dst[e], 0), n - 1);
    float4 v = ((const float4*)(hs + (size_t)s * DIM))[t];
    float* ap = agg + (size_t)d * DIM + t * 4;
    atomicAdd(ap + 0, v.x);
    atomicAdd(ap + 1, v.y);
    atomicAdd(ap + 2, v.z);
    atomicAdd(ap + 3, v.w);
}

// ---------------- h1 = relu(dinv*(agg + hs) + b1), written back into hs ----------------
__global__ __launch_bounds__(256) void relu_bias_kernel(const float4* __restrict__ agg,
                                                        float4* __restrict__ hs,
                                                        const float* __restrict__ dinv,
                                                        const float* __restrict__ b1,
                                                        int n) {
    long long i = (long long)blockIdx.x * 256 + threadIdx.x;   // over n*32 float4
    if (i >= (long long)n * (DIM / 4)) return;
    int node = (int)(i >> 5);
    int c4 = (int)(i & 31);
    float dv = dinv[node];
    float4 a = agg[i];
    float4 h = hs[i];
    float4 b = ((const float4*)b1)[c4];
    float4 r;
    r.x = fmaxf(fmaf(dv, a.x + h.x, b.x), 0.f);
    r.y = fmaxf(fmaf(dv, a.y + h.y, b.y), 0.f);
    r.z = fmaxf(fmaf(dv, a.z + h.z, b.z), 0.f);
    r.w = fmaxf(fmaf(dv, a.w + h.w, b.w), 0.f);
    hs[i] = r;
}

// ---------------- GEMM2: ss[n] = dinv[n] * dot(h1[n,:], W2) ; one wave per node ----------------
__global__ __launch_bounds__(256) void gemm2_kernel(const float* __restrict__ hr,
                                                    const float* __restrict__ W2,
                                                    const float* __restrict__ dinv,
                                                    float* __restrict__ ss, int n) {
    int wave = threadIdx.x >> 6;
    int lane = threadIdx.x & 63;
    int node = blockIdx.x * 4 + wave;
    if (node >= n) return;
    const float* row = hr + (size_t)node * DIM;
    float v = row[lane] * W2[lane] + row[lane + 64] * W2[lane + 64];
#pragma unroll
    for (int o = 32; o > 0; o >>= 1) v += __shfl_xor(v, o, 64);
    if (lane == 0) ss[node] = v * dinv[node];
}

// ---------------- scatter layer 2: out[dst] += ss[src] (scalar) ----------------
__global__ __launch_bounds__(256) void scatter2_kernel(const int* __restrict__ src,
                                                       const int* __restrict__ dst,
                                                       int E, int n,
                                                       const float* __restrict__ ss,
                                                       float* __restrict__ out) {
    int e = blockIdx.x * 256 + threadIdx.x;
    if (e >= E) return;
    int s = min(max(src[e], 0), n - 1);
    int d = min(max(dst[e], 0), n - 1);
    atomicAdd(&out[d], ss[s]);
}

// ---------------- out[n] = dinv[n]*(out[n] + ss[n]) + b2 ----------------
__global__ __launch_bounds__(256) void final_kernel(const float* __restrict__ ss,
                                                    const float* __restrict__ dinv,
                                                    const float* __restrict__ b2,
                                                    float* __restrict__ out, int n) {
    int i = blockIdx.x * 256 + threadIdx.x;
    if (i < n) out[i] = fmaf(dinv[i], out[i] + ss[i], b2[0]);
}

extern "C" void kernel_launch(void* const* d_in, const int* in_sizes, int n_in,
                              void* d_out, int out_size, void* d_ws, size_t ws_size,
                              hipStream_t stream) {
    const float* x   = (const float*)d_in[0];
    const int*   ei  = (const int*)d_in[1];     // int64 in reference -> passed as int32
    const float* W1  = (const float*)d_in[2];
    const float* b1  = (const float*)d_in[3];
    const float* W2  = (const float*)d_in[4];
    const float* b2  = (const float*)d_in[5];
    float*       out = (float*)d_out;

    const int n = in_sizes[0] / DIM;        // 50000
    const int E = in_sizes[1] / 2;          // 800000
    const int* srcI = ei;
    const int* dstI = ei + E;

    // workspace layout
    char* ws = (char*)d_ws;
    const size_t nvec = (((size_t)n * 4 + 511) & ~(size_t)511);   // bytes for dinv, aligned
    const size_t hbytes = (size_t)n * DIM * sizeof(float);        // 25.6 MB
    float* dinv = (float*)ws;
    float* hs   = (float*)(ws + nvec);
    float* agg  = (float*)(ws + nvec + hbytes);
    float* ss   = (float*)(ws + nvec + 2 * hbytes);

    hipMemsetAsync(dinv, 0, (size_t)n * sizeof(float), stream);
    hipMemsetAsync(agg, 0, hbytes, stream);
    hipMemsetAsync(out, 0, (size_t)n * sizeof(float), stream);

    deg_kernel<<<(E + 255) / 256, 256, 0, stream>>>(dstI, E, n, dinv);
    dinv_kernel<<<(n + 255) / 256, 256, 0, stream>>>(dinv, n);
    gemm1_kernel<<<(n + 63) / 64, 256, 0, stream>>>(x, W1, dinv, hs, n);
    {
        long long total = (long long)E * 32;
        int blocks = (int)((total + 255) / 256);
        scatter1_kernel<<<blocks, 256, 0, stream>>>(srcI, dstI, E, n, hs, agg);
    }
    {
        long long total = (long long)n * (DIM / 4);
        int blocks = (int)((total + 255) / 256);
        relu_bias_kernel<<<blocks, 256, 0, stream>>>((const float4*)agg, (float4*)hs, dinv, b1, n);
    }
    gemm2_kernel<<<(n + 3) / 4, 256, 0, stream>>>(hs, W2, dinv, ss, n);
    scatter2_kernel<<<(E + 255) / 256, 256, 0, stream>>>(srcI, dstI, E, n, ss, out);
    final_kernel<<<(n + 255) / 256, 256, 0, stream>>>(ss, dinv, b2, out, n);
}

// Round 4
// 325.599 us; speedup vs baseline: 4.7135x; 4.7135x over previous
//
#include <hip/hip_runtime.h>

#define DIM 128

// ---------------- degree histogram (int) ----------------
__global__ __launch_bounds__(256) void hist_kernel(const int* __restrict__ dst,
                                                   int E, int n, int* __restrict__ cnt) {
    int e = blockIdx.x * 256 + threadIdx.x;
    if (e < E) {
        int d = min(max(dst[e], 0), n - 1);
        atomicAdd(&cnt[d], 1);
    }
}

// ---------------- single-block scan: row_off (exclusive), dinv ----------------
__global__ __launch_bounds__(1024) void scan_kernel(const int* __restrict__ cnt,
                                                    int n, int E,
                                                    int* __restrict__ row_off,
                                                    float* __restrict__ dinv) {
    __shared__ int sdata[1024];
    const int t = threadIdx.x;
    const int chunk = (n + 1023) >> 10;
    const int base = t * chunk;
    const int lim = min(base + chunk, n);
    int s = 0;
    for (int i = base; i < lim; ++i) s += cnt[i];
    sdata[t] = s;
    __syncthreads();
    for (int off = 1; off < 1024; off <<= 1) {
        int v = (t >= off) ? sdata[t - off] : 0;
        __syncthreads();
        sdata[t] += v;
        __syncthreads();
    }
    int run = sdata[t] - s;   // exclusive prefix of this thread's chunk
    for (int i = base; i < lim; ++i) {
        row_off[i] = run;
        run += cnt[i];
        dinv[i] = rsqrtf((float)cnt[i] + 1.0f);   // +1 self-loop
    }
    if (t == 0) row_off[n] = E;
}

// ---------------- CSR fill: csr[row_off[d] + pos] = s ----------------
__global__ __launch_bounds__(256) void fill_kernel(const int* __restrict__ src,
                                                   const int* __restrict__ dst,
                                                   int E, int n,
                                                   const int* __restrict__ row_off,
                                                   int* __restrict__ cursor,
                                                   int* __restrict__ csr) {
    int e = blockIdx.x * 256 + threadIdx.x;
    if (e >= E) return;
    int s = min(max(src[e], 0), n - 1);
    int d = min(max(dst[e], 0), n - 1);
    int pos = atomicAdd(&cursor[d], 1);
    csr[row_off[d] + pos] = s;
}

// ---------------- GEMM1: hs[r][c] = dinv[r] * sum_k x[r][k]*W[k][c] ----------------
__global__ __launch_bounds__(256) void gemm1_kernel(const float* __restrict__ x,
                                                    const float* __restrict__ W,
                                                    const float* __restrict__ dinv,
                                                    float* __restrict__ hs, int n) {
    __shared__ float Ws[DIM][DIM];   // 64 KB
    __shared__ float xs[64][DIM];    // 32 KB
    const int tid = threadIdx.x;

    for (int i = tid; i < DIM * DIM / 4; i += 256)
        ((float4*)Ws)[i] = ((const float4*)W)[i];

    const int row0 = blockIdx.x * 64;
    for (int i = tid; i < 64 * DIM / 4; i += 256) {
        int r = i >> 5, c = i & 31;
        int gr = row0 + r;
        float4 v = make_float4(0.f, 0.f, 0.f, 0.f);
        if (gr < n) v = ((const float4*)(x + (size_t)gr * DIM))[c];
        ((float4*)(&xs[r][0]))[c] = v;
    }
    __syncthreads();

    const int tx = tid & 31;
    const int ty = tid >> 5;
    float acc[8][4];
#pragma unroll
    for (int r = 0; r < 8; ++r)
#pragma unroll
        for (int c = 0; c < 4; ++c) acc[r][c] = 0.f;

#pragma unroll 4
    for (int k = 0; k < DIM; ++k) {
        float4 wv = ((float4*)(&Ws[k][0]))[tx];
#pragma unroll
        for (int r = 0; r < 8; ++r) {
            float xv = xs[ty * 8 + r][k];
            acc[r][0] = fmaf(xv, wv.x, acc[r][0]);
            acc[r][1] = fmaf(xv, wv.y, acc[r][1]);
            acc[r][2] = fmaf(xv, wv.z, acc[r][2]);
            acc[r][3] = fmaf(xv, wv.w, acc[r][3]);
        }
    }

#pragma unroll
    for (int r = 0; r < 8; ++r) {
        int gr = row0 + ty * 8 + r;
        if (gr < n) {
            float dv = dinv[gr];
            float4 v = make_float4(acc[r][0] * dv, acc[r][1] * dv,
                                   acc[r][2] * dv, acc[r][3] * dv);
            ((float4*)(hs + (size_t)gr * DIM))[tx] = v;
        }
    }
}

// ---------------- fused: aggregate layer1 + bias + relu + GEMV(W2) -> ss ----------------
// One wave per node. Lanes 0-31 handle even CSR slots, 32-63 odd slots;
// each lane owns float4 index q = lane&31 of the 128-dim row.
__global__ __launch_bounds__(256) void gather1_kernel(const int* __restrict__ row_off,
                                                      const int* __restrict__ csr,
                                                      const float4* __restrict__ hs4,
                                                      const float* __restrict__ dinv,
                                                      const float* __restrict__ b1,
                                                      const float* __restrict__ W2,
                                                      float* __restrict__ ss, int n) {
    const int wave = threadIdx.x >> 6;
    const int lane = threadIdx.x & 63;
    const int node = blockIdx.x * 4 + wave;
    if (node >= n) return;

    const int rs = row_off[node];
    const int re = row_off[node + 1];
    const int q = lane & 31;
    const int half = lane >> 5;

    float4 acc = make_float4(0.f, 0.f, 0.f, 0.f);
    for (int j = rs + half; j < re; j += 2) {
        int s = csr[j];
        float4 v = hs4[(size_t)s * 32 + q];
        acc.x += v.x; acc.y += v.y; acc.z += v.z; acc.w += v.w;
    }
    // combine the two halves (lane L <-> L+32 hold the same q)
    acc.x += __shfl_xor(acc.x, 32, 64);
    acc.y += __shfl_xor(acc.y, 32, 64);
    acc.z += __shfl_xor(acc.z, 32, 64);
    acc.w += __shfl_xor(acc.w, 32, 64);

    // self-loop + bias + relu
    float dv = dinv[node];
    float4 hv = hs4[(size_t)node * 32 + q];
    float4 bv = ((const float4*)b1)[q];
    float4 h1;
    h1.x = fmaxf(fmaf(dv, acc.x + hv.x, bv.x), 0.f);
    h1.y = fmaxf(fmaf(dv, acc.y + hv.y, bv.y), 0.f);
    h1.z = fmaxf(fmaf(dv, acc.z + hv.z, bv.z), 0.f);
    h1.w = fmaxf(fmaf(dv, acc.w + hv.w, bv.w), 0.f);

    // layer-2 GEMV: ss[node] = dinv * dot(h1, W2)
    float4 wv = ((const float4*)W2)[q];
    float p = h1.x * wv.x + h1.y * wv.y + h1.z * wv.z + h1.w * wv.w;
#pragma unroll
    for (int o = 16; o > 0; o >>= 1) p += __shfl_xor(p, o, 64);
    if (lane == 0) ss[node] = p * dv;
}

// ---------------- layer-2 aggregate + finalize: out = dinv*(sum ss[src] + ss[i]) + b2 ----------------
__global__ __launch_bounds__(256) void gather2_kernel(const int* __restrict__ row_off,
                                                      const int* __restrict__ csr,
                                                      const float* __restrict__ ss,
                                                      const float* __restrict__ dinv,
                                                      const float* __restrict__ b2,
                                                      float* __restrict__ out, int n) {
    int i = blockIdx.x * 256 + threadIdx.x;
    if (i >= n) return;
    int rs = row_off[i], re = row_off[i + 1];
    float sum = 0.f;
    for (int j = rs; j < re; ++j) sum += ss[csr[j]];
    out[i] = fmaf(dinv[i], sum + ss[i], b2[0]);
}

extern "C" void kernel_launch(void* const* d_in, const int* in_sizes, int n_in,
                              void* d_out, int out_size, void* d_ws, size_t ws_size,
                              hipStream_t stream) {
    const float* x   = (const float*)d_in[0];
    const int*   ei  = (const int*)d_in[1];     // int64 ref -> harness passes int32
    const float* W1  = (const float*)d_in[2];
    const float* b1  = (const float*)d_in[3];
    const float* W2  = (const float*)d_in[4];
    const float* b2  = (const float*)d_in[5];
    float*       out = (float*)d_out;

    const int n = in_sizes[0] / DIM;        // 50000
    const int E = in_sizes[1] / 2;          // 800000
    const int* srcI = ei;
    const int* dstI = ei + E;

    // workspace layout (512B-aligned slices)
    char* ws = (char*)d_ws;
    size_t off = 0;
    auto alloc = [&](size_t bytes) { void* p = ws + off; off = (off + bytes + 511) & ~(size_t)511; return p; };
    float* dinv    = (float*)alloc((size_t)n * 4);
    int*   cnt     = (int*)  alloc((size_t)n * 4);
    int*   row_off = (int*)  alloc((size_t)(n + 1) * 4);
    int*   cursor  = (int*)  alloc((size_t)n * 4);
    int*   csr     = (int*)  alloc((size_t)E * 4);
    float* hs      = (float*)alloc((size_t)n * DIM * 4);
    float* ss      = (float*)alloc((size_t)n * 4);

    hipMemsetAsync(cnt, 0, (size_t)n * 4, stream);
    hipMemsetAsync(cursor, 0, (size_t)n * 4, stream);

    hist_kernel<<<(E + 255) / 256, 256, 0, stream>>>(dstI, E, n, cnt);
    scan_kernel<<<1, 1024, 0, stream>>>(cnt, n, E, row_off, dinv);
    fill_kernel<<<(E + 255) / 256, 256, 0, stream>>>(srcI, dstI, E, n, row_off, cursor, csr);
    gemm1_kernel<<<(n + 63) / 64, 256, 0, stream>>>(x, W1, dinv, hs, n);
    gather1_kernel<<<(n + 3) / 4, 256, 0, stream>>>(row_off, csr, (const float4*)hs,
                                                    dinv, b1, W2, ss, n);
    gather2_kernel<<<(n + 255) / 256, 256, 0, stream>>>(row_off, csr, ss, dinv, b2, out, n);
}

// Round 5
// 222.819 us; speedup vs baseline: 6.8878x; 1.4613x over previous
//
#include <hip/hip_runtime.h>

#define DIM 128
#define SCAN_TILE 2048   // 256 threads x 8 elements

// ---------------- degree histogram (int) ----------------
__global__ __launch_bounds__(256) void hist_kernel(const int* __restrict__ dst,
                                                   int E, int n, int* __restrict__ cnt) {
    int e = blockIdx.x * 256 + threadIdx.x;
    if (e < E) {
        int d = min(max(dst[e], 0), n - 1);
        atomicAdd(&cnt[d], 1);
    }
}

// ---------------- scan phase A: per-tile local exclusive scan + tile totals ----------------
__global__ __launch_bounds__(256) void scanA_kernel(const int* __restrict__ cnt, int n,
                                                    int* __restrict__ row_off,
                                                    int* __restrict__ tile_sum) {
    __shared__ int s[256];
    const int t = threadIdx.x;
    const int base = blockIdx.x * SCAN_TILE + t * 8;
    int v[8];
    int tsum = 0;
#pragma unroll
    for (int k = 0; k < 8; ++k) {
        int i = base + k;
        v[k] = (i < n) ? cnt[i] : 0;
        tsum += v[k];
    }
    s[t] = tsum;
    __syncthreads();
#pragma unroll
    for (int off = 1; off < 256; off <<= 1) {
        int u = (t >= off) ? s[t - off] : 0;
        __syncthreads();
        s[t] += u;
        __syncthreads();
    }
    int run = s[t] - tsum;   // exclusive prefix of this thread within tile
#pragma unroll
    for (int k = 0; k < 8; ++k) {
        int i = base + k;
        if (i < n) row_off[i] = run;
        run += v[k];
    }
    if (t == 255) tile_sum[blockIdx.x] = s[255];
}

// ---------------- scan phase B: exclusive scan of tile totals (single block) ----------------
__global__ __launch_bounds__(256) void scanB_kernel(int* __restrict__ tile_sum, int nb) {
    __shared__ int s[256];
    const int t = threadIdx.x;
    int v = (t < nb) ? tile_sum[t] : 0;
    s[t] = v;
    __syncthreads();
#pragma unroll
    for (int off = 1; off < 256; off <<= 1) {
        int u = (t >= off) ? s[t - off] : 0;
        __syncthreads();
        s[t] += u;
        __syncthreads();
    }
    if (t < nb) tile_sum[t] = s[t] - v;   // exclusive base per tile
}

// ---------------- scan phase C: add tile base; emit dinv; row_off[n]=E ----------------
__global__ __launch_bounds__(256) void scanC_kernel(int* __restrict__ row_off,
                                                    const int* __restrict__ tile_sum,
                                                    const int* __restrict__ cnt,
                                                    float* __restrict__ dinv,
                                                    int n, int E) {
    int i = blockIdx.x * 256 + threadIdx.x;
    if (i < n) {
        row_off[i] += tile_sum[i / SCAN_TILE];
        dinv[i] = rsqrtf((float)cnt[i] + 1.0f);   // +1 self-loop
    }
    if (i == 0) row_off[n] = E;
}

// ---------------- CSR fill: csr[row_off[d] + pos] = s ----------------
__global__ __launch_bounds__(256) void fill_kernel(const int* __restrict__ src,
                                                   const int* __restrict__ dst,
                                                   int E, int n,
                                                   const int* __restrict__ row_off,
                                                   int* __restrict__ cursor,
                                                   int* __restrict__ csr) {
    int e = blockIdx.x * 256 + threadIdx.x;
    if (e >= E) return;
    int s = min(max(src[e], 0), n - 1);
    int d = min(max(dst[e], 0), n - 1);
    int pos = atomicAdd(&cursor[d], 1);
    csr[row_off[d] + pos] = s;
}

// ---------------- GEMM1: hs[r][c] = dinv[r] * sum_k x[r][k]*W[k][c] ----------------
__global__ __launch_bounds__(256) void gemm1_kernel(const float* __restrict__ x,
                                                    const float* __restrict__ W,
                                                    const float* __restrict__ dinv,
                                                    float* __restrict__ hs, int n) {
    __shared__ float Ws[DIM][DIM];   // 64 KB
    __shared__ float xs[64][DIM];    // 32 KB
    const int tid = threadIdx.x;

    for (int i = tid; i < DIM * DIM / 4; i += 256)
        ((float4*)Ws)[i] = ((const float4*)W)[i];

    const int row0 = blockIdx.x * 64;
    for (int i = tid; i < 64 * DIM / 4; i += 256) {
        int r = i >> 5, c = i & 31;
        int gr = row0 + r;
        float4 v = make_float4(0.f, 0.f, 0.f, 0.f);
        if (gr < n) v = ((const float4*)(x + (size_t)gr * DIM))[c];
        ((float4*)(&xs[r][0]))[c] = v;
    }
    __syncthreads();

    const int tx = tid & 31;
    const int ty = tid >> 5;
    float acc[8][4];
#pragma unroll
    for (int r = 0; r < 8; ++r)
#pragma unroll
        for (int c = 0; c < 4; ++c) acc[r][c] = 0.f;

#pragma unroll 4
    for (int k = 0; k < DIM; ++k) {
        float4 wv = ((float4*)(&Ws[k][0]))[tx];
#pragma unroll
        for (int r = 0; r < 8; ++r) {
            float xv = xs[ty * 8 + r][k];
            acc[r][0] = fmaf(xv, wv.x, acc[r][0]);
            acc[r][1] = fmaf(xv, wv.y, acc[r][1]);
            acc[r][2] = fmaf(xv, wv.z, acc[r][2]);
            acc[r][3] = fmaf(xv, wv.w, acc[r][3]);
        }
    }

#pragma unroll
    for (int r = 0; r < 8; ++r) {
        int gr = row0 + ty * 8 + r;
        if (gr < n) {
            float dv = dinv[gr];
            float4 v = make_float4(acc[r][0] * dv, acc[r][1] * dv,
                                   acc[r][2] * dv, acc[r][3] * dv);
            ((float4*)(hs + (size_t)gr * DIM))[tx] = v;
        }
    }
}

// ---------------- fused: aggregate layer1 + bias + relu + GEMV(W2) -> ss ----------------
// One wave per node. Lanes 0-31 handle even CSR slots, 32-63 odd slots;
// each lane owns float4 index q = lane&31 of the 128-dim row.
__global__ __launch_bounds__(256) void gather1_kernel(const int* __restrict__ row_off,
                                                      const int* __restrict__ csr,
                                                      const float4* __restrict__ hs4,
                                                      const float* __restrict__ dinv,
                                                      const float* __restrict__ b1,
                                                      const float* __restrict__ W2,
                                                      float* __restrict__ ss, int n) {
    const int wave = threadIdx.x >> 6;
    const int lane = threadIdx.x & 63;
    const int node = blockIdx.x * 4 + wave;
    if (node >= n) return;

    const int rs = row_off[node];
    const int re = row_off[node + 1];
    const int q = lane & 31;
    const int half = lane >> 5;

    float4 acc = make_float4(0.f, 0.f, 0.f, 0.f);
    for (int j = rs + half; j < re; j += 2) {
        int s = csr[j];
        float4 v = hs4[(size_t)s * 32 + q];
        acc.x += v.x; acc.y += v.y; acc.z += v.z; acc.w += v.w;
    }
    // combine the two halves (lane L <-> L+32 hold the same q)
    acc.x += __shfl_xor(acc.x, 32, 64);
    acc.y += __shfl_xor(acc.y, 32, 64);
    acc.z += __shfl_xor(acc.z, 32, 64);
    acc.w += __shfl_xor(acc.w, 32, 64);

    // self-loop + bias + relu
    float dv = dinv[node];
    float4 hv = hs4[(size_t)node * 32 + q];
    float4 bv = ((const float4*)b1)[q];
    float4 h1;
    h1.x = fmaxf(fmaf(dv, acc.x + hv.x, bv.x), 0.f);
    h1.y = fmaxf(fmaf(dv, acc.y + hv.y, bv.y), 0.f);
    h1.z = fmaxf(fmaf(dv, acc.z + hv.z, bv.z), 0.f);
    h1.w = fmaxf(fmaf(dv, acc.w + hv.w, bv.w), 0.f);

    // layer-2 GEMV: ss[node] = dinv * dot(h1, W2)
    float4 wv = ((const float4*)W2)[q];
    float p = h1.x * wv.x + h1.y * wv.y + h1.z * wv.z + h1.w * wv.w;
#pragma unroll
    for (int o = 16; o > 0; o >>= 1) p += __shfl_xor(p, o, 64);
    if (lane == 0) ss[node] = p * dv;
}

// ---------------- layer-2 aggregate + finalize: out = dinv*(sum ss[src] + ss[i]) + b2 ----------------
__global__ __launch_bounds__(256) void gather2_kernel(const int* __restrict__ row_off,
                                                      const int* __restrict__ csr,
                                                      const float* __restrict__ ss,
                                                      const float* __restrict__ dinv,
                                                      const float* __restrict__ b2,
                                                      float* __restrict__ out, int n) {
    int i = blockIdx.x * 256 + threadIdx.x;
    if (i >= n) return;
    int rs = row_off[i], re = row_off[i + 1];
    float sum = 0.f;
    for (int j = rs; j < re; ++j) sum += ss[csr[j]];
    out[i] = fmaf(dinv[i], sum + ss[i], b2[0]);
}

extern "C" void kernel_launch(void* const* d_in, const int* in_sizes, int n_in,
                              void* d_out, int out_size, void* d_ws, size_t ws_size,
                              hipStream_t stream) {
    const float* x   = (const float*)d_in[0];
    const int*   ei  = (const int*)d_in[1];     // int64 ref -> harness passes int32
    const float* W1  = (const float*)d_in[2];
    const float* b1  = (const float*)d_in[3];
    const float* W2  = (const float*)d_in[4];
    const float* b2  = (const float*)d_in[5];
    float*       out = (float*)d_out;

    const int n = in_sizes[0] / DIM;        // 50000
    const int E = in_sizes[1] / 2;          // 800000
    const int* srcI = ei;
    const int* dstI = ei + E;
    const int nb = (n + SCAN_TILE - 1) / SCAN_TILE;   // 25 tiles (<=256)

    // workspace layout (512B-aligned slices)
    char* ws = (char*)d_ws;
    size_t off = 0;
    auto alloc = [&](size_t bytes) { void* p = ws + off; off = (off + bytes + 511) & ~(size_t)511; return p; };
    float* dinv     = (float*)alloc((size_t)n * 4);
    int*   cnt      = (int*)  alloc((size_t)n * 4);
    int*   row_off  = (int*)  alloc((size_t)(n + 1) * 4);
    int*   cursor   = (int*)  alloc((size_t)n * 4);
    int*   tile_sum = (int*)  alloc((size_t)256 * 4);
    int*   csr      = (int*)  alloc((size_t)E * 4);
    float* hs       = (float*)alloc((size_t)n * DIM * 4);
    float* ss       = (float*)alloc((size_t)n * 4);

    hipMemsetAsync(cnt, 0, (size_t)n * 4, stream);
    hipMemsetAsync(cursor, 0, (size_t)n * 4, stream);

    hist_kernel<<<(E + 255) / 256, 256, 0, stream>>>(dstI, E, n, cnt);
    scanA_kernel<<<nb, 256, 0, stream>>>(cnt, n, row_off, tile_sum);
    scanB_kernel<<<1, 256, 0, stream>>>(tile_sum, nb);
    scanC_kernel<<<(n + 255) / 256, 256, 0, stream>>>(row_off, tile_sum, cnt, dinv, n, E);
    fill_kernel<<<(E + 255) / 256, 256, 0, stream>>>(srcI, dstI, E, n, row_off, cursor, csr);
    gemm1_kernel<<<(n + 63) / 64, 256, 0, stream>>>(x, W1, dinv, hs, n);
    gather1_kernel<<<(n + 3) / 4, 256, 0, stream>>>(row_off, csr, (const float4*)hs,
                                                    dinv, b1, W2, ss, n);
    gather2_kernel<<<(n + 255) / 256, 256, 0, stream>>>(row_off, csr, ss, dinv, b2, out, n);
}

// Round 6
// 216.940 us; speedup vs baseline: 7.0744x; 1.0271x over previous
//
#include <hip/hip_runtime.h>

#define DIM 128
#define SCAN_TILE 2048   // 256 threads x 8 elements

// ---------------- degree histogram (int) ----------------
__global__ __launch_bounds__(256) void hist_kernel(const int* __restrict__ dst,
                                                   int E, int n, int* __restrict__ cnt) {
    int e = blockIdx.x * 256 + threadIdx.x;
    if (e < E) {
        int d = min(max(dst[e], 0), n - 1);
        atomicAdd(&cnt[d], 1);
    }
}

// ---------------- scan phase A: per-tile local exclusive scan + tile totals ----------------
__global__ __launch_bounds__(256) void scanA_kernel(const int* __restrict__ cnt, int n,
                                                    int* __restrict__ row_off,
                                                    int* __restrict__ tile_sum) {
    __shared__ int s[256];
    const int t = threadIdx.x;
    const int base = blockIdx.x * SCAN_TILE + t * 8;
    int v[8];
    int tsum = 0;
#pragma unroll
    for (int k = 0; k < 8; ++k) {
        int i = base + k;
        v[k] = (i < n) ? cnt[i] : 0;
        tsum += v[k];
    }
    s[t] = tsum;
    __syncthreads();
#pragma unroll
    for (int off = 1; off < 256; off <<= 1) {
        int u = (t >= off) ? s[t - off] : 0;
        __syncthreads();
        s[t] += u;
        __syncthreads();
    }
    int run = s[t] - tsum;   // exclusive prefix of this thread within tile
#pragma unroll
    for (int k = 0; k < 8; ++k) {
        int i = base + k;
        if (i < n) row_off[i] = run;
        run += v[k];
    }
    if (t == 255) tile_sum[blockIdx.x] = s[255];
}

// ---------------- scan phase B: exclusive scan of tile totals (single block) ----------------
__global__ __launch_bounds__(256) void scanB_kernel(int* __restrict__ tile_sum, int nb) {
    __shared__ int s[256];
    const int t = threadIdx.x;
    int v = (t < nb) ? tile_sum[t] : 0;
    s[t] = v;
    __syncthreads();
#pragma unroll
    for (int off = 1; off < 256; off <<= 1) {
        int u = (t >= off) ? s[t - off] : 0;
        __syncthreads();
        s[t] += u;
        __syncthreads();
    }
    if (t < nb) tile_sum[t] = s[t] - v;   // exclusive base per tile
}

// ---------------- scan phase C: add tile base; emit dinv; row_off[n]=E ----------------
__global__ __launch_bounds__(256) void scanC_kernel(int* __restrict__ row_off,
                                                    const int* __restrict__ tile_sum,
                                                    const int* __restrict__ cnt,
                                                    float* __restrict__ dinv,
                                                    int n, int E) {
    int i = blockIdx.x * 256 + threadIdx.x;
    if (i < n) {
        row_off[i] += tile_sum[i / SCAN_TILE];
        dinv[i] = rsqrtf((float)cnt[i] + 1.0f);   // +1 self-loop
    }
    if (i == 0) row_off[n] = E;
}

// ---------------- CSR fill: csr[row_off[d] + pos] = s ----------------
__global__ __launch_bounds__(256) void fill_kernel(const int* __restrict__ src,
                                                   const int* __restrict__ dst,
                                                   int E, int n,
                                                   const int* __restrict__ row_off,
                                                   int* __restrict__ cursor,
                                                   int* __restrict__ csr) {
    int e = blockIdx.x * 256 + threadIdx.x;
    if (e >= E) return;
    int s = min(max(src[e], 0), n - 1);
    int d = min(max(dst[e], 0), n - 1);
    int pos = atomicAdd(&cursor[d], 1);
    csr[row_off[d] + pos] = s;
}

// ---------------- GEMM1: hs[r][c] = dinv[r] * sum_k x[r][k]*W[k][c] ----------------
// 512 threads, 128 rows/block. Only W staged in LDS (64KB -> 2 blocks/CU,
// 16 waves/CU). x read directly from global (float4, lane-broadcast, L1/L2
// served). 1 ds_read_b128 per k. x chunk prefetched one step ahead.
__global__ __launch_bounds__(512, 4) void gemm1_kernel(const float* __restrict__ x,
                                                       const float* __restrict__ W,
                                                       const float* __restrict__ dinv,
                                                       float* __restrict__ hs, int n) {
    __shared__ float Ws[DIM * DIM];   // 64 KB, [k][c] row-major
    const int tid = threadIdx.x;

    for (int i = tid; i < DIM * DIM / 4; i += 512)
        ((float4*)Ws)[i] = ((const float4*)W)[i];
    __syncthreads();

    const int tx = tid & 31;          // cols 4*tx .. 4*tx+3
    const int ty = tid >> 5;          // 0..15 -> rows 8*ty .. 8*ty+7
    const int row0 = blockIdx.x * 128 + ty * 8;
    const float4* x4 = (const float4*)x;

    // clamped row indices (safe loads; stores guarded)
    int rowi[8];
#pragma unroll
    for (int r = 0; r < 8; ++r) {
        int gr = row0 + r;
        rowi[r] = (gr < n) ? gr : 0;
    }

    float acc[8][4];
#pragma unroll
    for (int r = 0; r < 8; ++r)
#pragma unroll
        for (int c = 0; c < 4; ++c) acc[r][c] = 0.f;

    float4 xv[8], xn[8];
#pragma unroll
    for (int r = 0; r < 8; ++r) xv[r] = x4[(size_t)rowi[r] * 32 + 0];

#pragma unroll 1
    for (int k0 = 0; k0 < DIM; k0 += 4) {
        const int nk = (k0 >> 2) + 1;
        if (nk < 32) {
#pragma unroll
            for (int r = 0; r < 8; ++r) xn[r] = x4[(size_t)rowi[r] * 32 + nk];
        }
#pragma unroll
        for (int kk = 0; kk < 4; ++kk) {
            float4 wv = ((const float4*)(Ws + (size_t)(k0 + kk) * DIM))[tx];
#pragma unroll
            for (int r = 0; r < 8; ++r) {
                const float xk = (kk == 0) ? xv[r].x : (kk == 1) ? xv[r].y
                               : (kk == 2) ? xv[r].z : xv[r].w;
                acc[r][0] = fmaf(xk, wv.x, acc[r][0]);
                acc[r][1] = fmaf(xk, wv.y, acc[r][1]);
                acc[r][2] = fmaf(xk, wv.z, acc[r][2]);
                acc[r][3] = fmaf(xk, wv.w, acc[r][3]);
            }
        }
#pragma unroll
        for (int r = 0; r < 8; ++r) xv[r] = xn[r];
    }

#pragma unroll
    for (int r = 0; r < 8; ++r) {
        int gr = row0 + r;
        if (gr < n) {
            float dv = dinv[gr];
            float4 v = make_float4(acc[r][0] * dv, acc[r][1] * dv,
                                   acc[r][2] * dv, acc[r][3] * dv);
            ((float4*)(hs + (size_t)gr * DIM))[tx] = v;
        }
    }
}

// ---------------- fused: aggregate layer1 + bias + relu + GEMV(W2) -> ss ----------------
// One wave per node. Lanes 0-31 handle even CSR slots, 32-63 odd slots;
// each lane owns float4 index q = lane&31 of the 128-dim row.
__global__ __launch_bounds__(256) void gather1_kernel(const int* __restrict__ row_off,
                                                      const int* __restrict__ csr,
                                                      const float4* __restrict__ hs4,
                                                      const float* __restrict__ dinv,
                                                      const float* __restrict__ b1,
                                                      const float* __restrict__ W2,
                                                      float* __restrict__ ss, int n) {
    const int wave = threadIdx.x >> 6;
    const int lane = threadIdx.x & 63;
    const int node = blockIdx.x * 4 + wave;
    if (node >= n) return;

    const int rs = row_off[node];
    const int re = row_off[node + 1];
    const int q = lane & 31;
    const int half = lane >> 5;

    float4 acc = make_float4(0.f, 0.f, 0.f, 0.f);
    for (int j = rs + half; j < re; j += 2) {
        int s = csr[j];
        float4 v = hs4[(size_t)s * 32 + q];
        acc.x += v.x; acc.y += v.y; acc.z += v.z; acc.w += v.w;
    }
    // combine the two halves (lane L <-> L+32 hold the same q)
    acc.x += __shfl_xor(acc.x, 32, 64);
    acc.y += __shfl_xor(acc.y, 32, 64);
    acc.z += __shfl_xor(acc.z, 32, 64);
    acc.w += __shfl_xor(acc.w, 32, 64);

    // self-loop + bias + relu
    float dv = dinv[node];
    float4 hv = hs4[(size_t)node * 32 + q];
    float4 bv = ((const float4*)b1)[q];
    float4 h1;
    h1.x = fmaxf(fmaf(dv, acc.x + hv.x, bv.x), 0.f);
    h1.y = fmaxf(fmaf(dv, acc.y + hv.y, bv.y), 0.f);
    h1.z = fmaxf(fmaf(dv, acc.z + hv.z, bv.z), 0.f);
    h1.w = fmaxf(fmaf(dv, acc.w + hv.w, bv.w), 0.f);

    // layer-2 GEMV: ss[node] = dinv * dot(h1, W2)
    float4 wv = ((const float4*)W2)[q];
    float p = h1.x * wv.x + h1.y * wv.y + h1.z * wv.z + h1.w * wv.w;
#pragma unroll
    for (int o = 16; o > 0; o >>= 1) p += __shfl_xor(p, o, 64);
    if (lane == 0) ss[node] = p * dv;
}

// ---------------- layer-2 aggregate + finalize: out = dinv*(sum ss[src] + ss[i]) + b2 ----------------
__global__ __launch_bounds__(256) void gather2_kernel(const int* __restrict__ row_off,
                                                      const int* __restrict__ csr,
                                                      const float* __restrict__ ss,
                                                      const float* __restrict__ dinv,
                                                      const float* __restrict__ b2,
                                                      float* __restrict__ out, int n) {
    int i = blockIdx.x * 256 + threadIdx.x;
    if (i >= n) return;
    int rs = row_off[i], re = row_off[i + 1];
    float sum = 0.f;
    for (int j = rs; j < re; ++j) sum += ss[csr[j]];
    out[i] = fmaf(dinv[i], sum + ss[i], b2[0]);
}

extern "C" void kernel_launch(void* const* d_in, const int* in_sizes, int n_in,
                              void* d_out, int out_size, void* d_ws, size_t ws_size,
                              hipStream_t stream) {
    const float* x   = (const float*)d_in[0];
    const int*   ei  = (const int*)d_in[1];     // int64 ref -> harness passes int32
    const float* W1  = (const float*)d_in[2];
    const float* b1  = (const float*)d_in[3];
    const float* W2  = (const float*)d_in[4];
    const float* b2  = (const float*)d_in[5];
    float*       out = (float*)d_out;

    const int n = in_sizes[0] / DIM;        // 50000
    const int E = in_sizes[1] / 2;          // 800000
    const int* srcI = ei;
    const int* dstI = ei + E;
    const int nb = (n + SCAN_TILE - 1) / SCAN_TILE;   // 25 tiles (<=256)

    // workspace layout (512B-aligned slices)
    char* ws = (char*)d_ws;
    size_t off = 0;
    auto alloc = [&](size_t bytes) { void* p = ws + off; off = (off + bytes + 511) & ~(size_t)511; return p; };
    float* dinv     = (float*)alloc((size_t)n * 4);
    int*   cnt      = (int*)  alloc((size_t)n * 4);
    int*   row_off  = (int*)  alloc((size_t)(n + 1) * 4);
    int*   cursor   = (int*)  alloc((size_t)n * 4);
    int*   tile_sum = (int*)  alloc((size_t)256 * 4);
    int*   csr      = (int*)  alloc((size_t)E * 4);
    float* hs       = (float*)alloc((size_t)n * DIM * 4);
    float* ss       = (float*)alloc((size_t)n * 4);

    hipMemsetAsync(cnt, 0, (size_t)n * 4, stream);
    hipMemsetAsync(cursor, 0, (size_t)n * 4, stream);

    hist_kernel<<<(E + 255) / 256, 256, 0, stream>>>(dstI, E, n, cnt);
    scanA_kernel<<<nb, 256, 0, stream>>>(cnt, n, row_off, tile_sum);
    scanB_kernel<<<1, 256, 0, stream>>>(tile_sum, nb);
    scanC_kernel<<<(n + 255) / 256, 256, 0, stream>>>(row_off, tile_sum, cnt, dinv, n, E);
    fill_kernel<<<(E + 255) / 256, 256, 0, stream>>>(srcI, dstI, E, n, row_off, cursor, csr);
    gemm1_kernel<<<(n + 127) / 128, 512, 0, stream>>>(x, W1, dinv, hs, n);
    gather1_kernel<<<(n + 3) / 4, 256, 0, stream>>>(row_off, csr, (const float4*)hs,
                                                    dinv, b1, W2, ss, n);
    gather2_kernel<<<(n + 255) / 256, 256, 0, stream>>>(row_off, csr, ss, dinv, b2, out, n);
}

// Round 8
// 192.905 us; speedup vs baseline: 7.9559x; 1.1246x over previous
//
#include <hip/hip_runtime.h>
#include <hip/hip_fp16.h>

#define DIM 128
#define SCAN_TILE 2048   // 256 threads x 8 elements

// ---- fp16 quad pack/unpack (4 halves in a uint2) ----
__device__ __forceinline__ float4 h4_to_f4(uint2 u) {
    __half2 a = __builtin_bit_cast(__half2, u.x);
    __half2 b = __builtin_bit_cast(__half2, u.y);
    float2 fa = __half22float2(a), fb = __half22float2(b);
    return make_float4(fa.x, fa.y, fb.x, fb.y);
}
__device__ __forceinline__ uint2 f4_to_h4(float4 v) {
    __half2 a = __floats2half2_rn(v.x, v.y);
    __half2 b = __floats2half2_rn(v.z, v.w);
    return make_uint2(__builtin_bit_cast(unsigned, a), __builtin_bit_cast(unsigned, b));
}

// ---------------- degree histogram (int) ----------------
__global__ __launch_bounds__(256) void hist_kernel(const int* __restrict__ dst,
                                                   int E, int n, int* __restrict__ cnt) {
    int e = blockIdx.x * 256 + threadIdx.x;
    if (e < E) {
        int d = min(max(dst[e], 0), n - 1);
        atomicAdd(&cnt[d], 1);
    }
}

// ---------------- scan phase A ----------------
__global__ __launch_bounds__(256) void scanA_kernel(const int* __restrict__ cnt, int n,
                                                    int* __restrict__ row_off,
                                                    int* __restrict__ tile_sum) {
    __shared__ int s[256];
    const int t = threadIdx.x;
    const int base = blockIdx.x * SCAN_TILE + t * 8;
    int v[8];
    int tsum = 0;
#pragma unroll
    for (int k = 0; k < 8; ++k) {
        int i = base + k;
        v[k] = (i < n) ? cnt[i] : 0;
        tsum += v[k];
    }
    s[t] = tsum;
    __syncthreads();
#pragma unroll
    for (int off = 1; off < 256; off <<= 1) {
        int u = (t >= off) ? s[t - off] : 0;
        __syncthreads();
        s[t] += u;
        __syncthreads();
    }
    int run = s[t] - tsum;
#pragma unroll
    for (int k = 0; k < 8; ++k) {
        int i = base + k;
        if (i < n) row_off[i] = run;
        run += v[k];
    }
    if (t == 255) tile_sum[blockIdx.x] = s[255];
}

// ---------------- scan phase B ----------------
__global__ __launch_bounds__(256) void scanB_kernel(int* __restrict__ tile_sum, int nb) {
    __shared__ int s[256];
    const int t = threadIdx.x;
    int v = (t < nb) ? tile_sum[t] : 0;
    s[t] = v;
    __syncthreads();
#pragma unroll
    for (int off = 1; off < 256; off <<= 1) {
        int u = (t >= off) ? s[t - off] : 0;
        __syncthreads();
        s[t] += u;
        __syncthreads();
    }
    if (t < nb) tile_sum[t] = s[t] - v;
}

// ---------------- scan phase C ----------------
__global__ __launch_bounds__(256) void scanC_kernel(int* __restrict__ row_off,
                                                    const int* __restrict__ tile_sum,
                                                    const int* __restrict__ cnt,
                                                    float* __restrict__ dinv,
                                                    int n, int E) {
    int i = blockIdx.x * 256 + threadIdx.x;
    if (i < n) {
        row_off[i] += tile_sum[i / SCAN_TILE];
        dinv[i] = rsqrtf((float)cnt[i] + 1.0f);
    }
    if (i == 0) row_off[n] = E;
}

// ---------------- CSR fill ----------------
__global__ __launch_bounds__(256) void fill_kernel(const int* __restrict__ src,
                                                   const int* __restrict__ dst,
                                                   int E, int n,
                                                   const int* __restrict__ row_off,
                                                   int* __restrict__ cursor,
                                                   int* __restrict__ csr) {
    int e = blockIdx.x * 256 + threadIdx.x;
    if (e >= E) return;
    int s = min(max(src[e], 0), n - 1);
    int d = min(max(dst[e], 0), n - 1);
    int pos = atomicAdd(&cursor[d], 1);
    csr[row_off[d] + pos] = s;
}

// ---------------- GEMM1: hs[r][c] = fp16( dinv[r] * sum_k x[r][k]*W[k][c] ) ----------------
// No LDS: W streamed from L1/L2 (~200 MB L2 traffic total, well under ceiling).
// 256 threads, 64 rows/block, 8 rows x 4 cols per thread, barrier-free pipelining.
__global__ __launch_bounds__(256) void gemm1_kernel(const float* __restrict__ x,
                                                    const float* __restrict__ W,
                                                    const float* __restrict__ dinv,
                                                    __half* __restrict__ hs, int n) {
    const int tid = threadIdx.x;
    const int tx = tid & 31;          // cols 4*tx .. 4*tx+3
    const int ty = tid >> 5;          // 0..7 -> rows 8*ty .. 8*ty+7
    const int row0 = blockIdx.x * 64 + ty * 8;
    const float4* x4 = (const float4*)x;
    const float4* W4 = (const float4*)W;   // W4[k*32 + c]

    int rowi[8];
#pragma unroll
    for (int r = 0; r < 8; ++r) {
        int gr = row0 + r;
        rowi[r] = (gr < n) ? gr : 0;
    }

    float acc[8][4];
#pragma unroll
    for (int r = 0; r < 8; ++r)
#pragma unroll
        for (int c = 0; c < 4; ++c) acc[r][c] = 0.f;

#pragma unroll 1
    for (int k0 = 0; k0 < DIM; k0 += 4) {
        float4 wv[4];
#pragma unroll
        for (int kk = 0; kk < 4; ++kk) wv[kk] = W4[(k0 + kk) * 32 + tx];
        float4 xv[8];
#pragma unroll
        for (int r = 0; r < 8; ++r) xv[r] = x4[(size_t)rowi[r] * 32 + (k0 >> 2)];
#pragma unroll
        for (int kk = 0; kk < 4; ++kk) {
#pragma unroll
            for (int r = 0; r < 8; ++r) {
                const float xk = (kk == 0) ? xv[r].x : (kk == 1) ? xv[r].y
                               : (kk == 2) ? xv[r].z : xv[r].w;
                acc[r][0] = fmaf(xk, wv[kk].x, acc[r][0]);
                acc[r][1] = fmaf(xk, wv[kk].y, acc[r][1]);
                acc[r][2] = fmaf(xk, wv[kk].z, acc[r][2]);
                acc[r][3] = fmaf(xk, wv[kk].w, acc[r][3]);
            }
        }
    }

#pragma unroll
    for (int r = 0; r < 8; ++r) {
        int gr = row0 + r;
        if (gr < n) {
            float dv = dinv[gr];
            float4 v = make_float4(acc[r][0] * dv, acc[r][1] * dv,
                                   acc[r][2] * dv, acc[r][3] * dv);
            ((uint2*)(hs + (size_t)gr * DIM))[tx] = f4_to_h4(v);
        }
    }
}

// ---------------- fused: aggregate layer1 + bias + relu + GEMV(W2) -> ss ----------------
// One wave per node. Lanes 0-31 take even CSR slots, 32-63 odd slots (per-lane
// scalar csr loads, L1 broadcast — NO cross-lane ops in divergent code).
// 2-way unroll: two independent gathers in flight. Lane q = lane&31 owns dims
// 4q..4q+3 (fp16 row = 32 uint2). Cross-lane combines happen only after both
// loops, where the wave has re-converged.
__global__ __launch_bounds__(256) void gather1_kernel(const int* __restrict__ row_off,
                                                      const int* __restrict__ csr,
                                                      const __half* __restrict__ hs,
                                                      const float* __restrict__ dinv,
                                                      const float* __restrict__ b1,
                                                      const float* __restrict__ W2,
                                                      float* __restrict__ ss, int n) {
    const int wave = threadIdx.x >> 6;
    const int lane = threadIdx.x & 63;
    const int node = blockIdx.x * 4 + wave;
    if (node >= n) return;

    const int rs = row_off[node];
    const int re = row_off[node + 1];
    const int q = lane & 31;
    const int half = lane >> 5;
    const uint2* hs2 = (const uint2*)hs;   // 32 uint2 per row

    float4 a0 = make_float4(0.f, 0.f, 0.f, 0.f);
    float4 a1 = make_float4(0.f, 0.f, 0.f, 0.f);

    int j = rs + half;
    for (; j + 2 < re; j += 4) {
        int s0 = csr[j];
        int s1 = csr[j + 2];
        float4 v0 = h4_to_f4(hs2[(size_t)s0 * 32 + q]);
        float4 v1 = h4_to_f4(hs2[(size_t)s1 * 32 + q]);
        a0.x += v0.x; a0.y += v0.y; a0.z += v0.z; a0.w += v0.w;
        a1.x += v1.x; a1.y += v1.y; a1.z += v1.z; a1.w += v1.w;
    }
    for (; j < re; j += 2) {
        int s = csr[j];
        float4 v = h4_to_f4(hs2[(size_t)s * 32 + q]);
        a0.x += v.x; a0.y += v.y; a0.z += v.z; a0.w += v.w;
    }
    float4 acc = make_float4(a0.x + a1.x, a0.y + a1.y, a0.z + a1.z, a0.w + a1.w);

    // combine halves (lane L <-> L+32 hold the same q) — wave re-converged here
    acc.x += __shfl_xor(acc.x, 32, 64);
    acc.y += __shfl_xor(acc.y, 32, 64);
    acc.z += __shfl_xor(acc.z, 32, 64);
    acc.w += __shfl_xor(acc.w, 32, 64);

    // self-loop + bias + relu
    float dv = dinv[node];
    float4 hv = h4_to_f4(hs2[(size_t)node * 32 + q]);
    float4 bv = ((const float4*)b1)[q];
    float4 h1;
    h1.x = fmaxf(fmaf(dv, acc.x + hv.x, bv.x), 0.f);
    h1.y = fmaxf(fmaf(dv, acc.y + hv.y, bv.y), 0.f);
    h1.z = fmaxf(fmaf(dv, acc.z + hv.z, bv.z), 0.f);
    h1.w = fmaxf(fmaf(dv, acc.w + hv.w, bv.w), 0.f);

    // layer-2 GEMV: ss[node] = dinv * dot(h1, W2)
    float4 wv = ((const float4*)W2)[q];
    float p = h1.x * wv.x + h1.y * wv.y + h1.z * wv.z + h1.w * wv.w;
#pragma unroll
    for (int o = 16; o > 0; o >>= 1) p += __shfl_xor(p, o, 64);
    if (lane == 0) ss[node] = p * dv;
}

// ---------------- layer-2 aggregate + finalize ----------------
__global__ __launch_bounds__(256) void gather2_kernel(const int* __restrict__ row_off,
                                                      const int* __restrict__ csr,
                                                      const float* __restrict__ ss,
                                                      const float* __restrict__ dinv,
                                                      const float* __restrict__ b2,
                                                      float* __restrict__ out, int n) {
    int i = blockIdx.x * 256 + threadIdx.x;
    if (i >= n) return;
    int rs = row_off[i], re = row_off[i + 1];
    float sum = 0.f;
    for (int j = rs; j < re; ++j) sum += ss[csr[j]];
    out[i] = fmaf(dinv[i], sum + ss[i], b2[0]);
}

extern "C" void kernel_launch(void* const* d_in, const int* in_sizes, int n_in,
                              void* d_out, int out_size, void* d_ws, size_t ws_size,
                              hipStream_t stream) {
    const float* x   = (const float*)d_in[0];
    const int*   ei  = (const int*)d_in[1];     // int64 ref -> harness passes int32
    const float* W1  = (const float*)d_in[2];
    const float* b1  = (const float*)d_in[3];
    const float* W2  = (const float*)d_in[4];
    const float* b2  = (const float*)d_in[5];
    float*       out = (float*)d_out;

    const int n = in_sizes[0] / DIM;        // 50000
    const int E = in_sizes[1] / 2;          // 800000
    const int* srcI = ei;
    const int* dstI = ei + E;
    const int nb = (n + SCAN_TILE - 1) / SCAN_TILE;   // 25 tiles (<=256)

    // workspace layout (512B-aligned slices)
    char* ws = (char*)d_ws;
    size_t off = 0;
    auto alloc = [&](size_t bytes) { void* p = ws + off; off = (off + bytes + 511) & ~(size_t)511; return p; };
    float*  dinv     = (float*)alloc((size_t)n * 4);
    int*    cnt      = (int*)  alloc((size_t)n * 4);
    int*    row_off  = (int*)  alloc((size_t)(n + 1) * 4);
    int*    cursor   = (int*)  alloc((size_t)n * 4);
    int*    tile_sum = (int*)  alloc((size_t)256 * 4);
    int*    csr      = (int*)  alloc((size_t)E * 4);
    __half* hs       = (__half*)alloc((size_t)n * DIM * 2);
    float*  ss       = (float*)alloc((size_t)n * 4);

    hipMemsetAsync(cnt, 0, (size_t)n * 4, stream);
    hipMemsetAsync(cursor, 0, (size_t)n * 4, stream);

    hist_kernel<<<(E + 255) / 256, 256, 0, stream>>>(dstI, E, n, cnt);
    scanA_kernel<<<nb, 256, 0, stream>>>(cnt, n, row_off, tile_sum);
    scanB_kernel<<<1, 256, 0, stream>>>(tile_sum, nb);
    scanC_kernel<<<(n + 255) / 256, 256, 0, stream>>>(row_off, tile_sum, cnt, dinv, n, E);
    fill_kernel<<<(E + 255) / 256, 256, 0, stream>>>(srcI, dstI, E, n, row_off, cursor, csr);
    gemm1_kernel<<<(n + 63) / 64, 256, 0, stream>>>(x, W1, dinv, hs, n);
    gather1_kernel<<<(n + 3) / 4, 256, 0, stream>>>(row_off, csr, hs, dinv, b1, W2, ss, n);
    gather2_kernel<<<(n + 255) / 256, 256, 0, stream>>>(row_off, csr, ss, dinv, b2, out, n);
}